// Round 2
// baseline (1126.642 us; speedup 1.0000x reference)
//
#include <hip/hip_runtime.h>

// FBSNN: 50-step SDE loop, two 2-64-64-1 MLPs (Q control, Y value + dY/dy tangent).
// Strategy: wave = 64 samples for all 50 steps. 64x64 layers via mfma_f32_16x16x32_f16
// (fp32 accum). Layer-1/layer-3 + SDE update in fp32 vector math. Weights in LDS
// (W2 transposed, stride 72 halves: 16B-aligned b128 reads, <=2-way bank conflicts).

#define B_TOT 262144
#define NSTEPS 50
#define DT 0.01f
#define SIGMA 0.5f

typedef _Float16 half8_t __attribute__((ext_vector_type(8)));
typedef __fp16   fp16x2  __attribute__((ext_vector_type(2)));
typedef float    float4_t __attribute__((ext_vector_type(4)));

// cvt_pkrtz returns __fp16x2; MFMA wants _Float16x8 — same bits, punned via union.
union H8 { half8_t v; fp16x2 p[4]; };

#define MFMA(a, b, c) __builtin_amdgcn_mfma_f32_16x16x32_f16((a), (b), (c), 0, 0, 0)

__global__ void zero_out_k(float* out) { out[0] = 0.f; }

__global__ __launch_bounds__(256) void fbsnn_k(
    const float* __restrict__ dW,  const float* __restrict__ y0i,
    const float* __restrict__ Yw1, const float* __restrict__ Yb1,
    const float* __restrict__ Yw2, const float* __restrict__ Yb2,
    const float* __restrict__ Yw3, const float* __restrict__ Yb3,
    const float* __restrict__ Qw1, const float* __restrict__ Qb1,
    const float* __restrict__ Qw2, const float* __restrict__ Qb2,
    const float* __restrict__ Qw3, const float* __restrict__ Qb3,
    float* __restrict__ out)
{
    // W2 transposed: w2[n*72 + k] = W2[k*64 + n]; stride 72 (144B) keeps b128 aligned.
    __shared__ __align__(16) _Float16 w2q[64 * 72];
    __shared__ __align__(16) _Float16 w2y[64 * 72];
    // layer1 consts fp32: [0..63]=w1_t row, [64..127]=w1_y row, [128..191]=b1
    __shared__ __align__(16) float l1q[192];
    __shared__ __align__(16) float l1y[192];
    // per-wave sample-layout exchange buffers
    __shared__ __align__(16) float xbA[4][64];
    __shared__ __align__(16) float xbB[4][64];
    __shared__ float rb[4];

    const int tid = threadIdx.x;

    #pragma unroll
    for (int it = 0; it < 16; ++it) {
        int e = it * 256 + tid;
        int k = e >> 6, n = e & 63;
        w2q[n * 72 + k] = (_Float16)Qw2[e];
        w2y[n * 72 + k] = (_Float16)Yw2[e];
    }
    if (tid < 64) {
        l1q[tid] = Qw1[tid]; l1q[64 + tid] = Qw1[64 + tid]; l1q[128 + tid] = Qb1[tid];
        l1y[tid] = Yw1[tid]; l1y[64 + tid] = Yw1[64 + tid]; l1y[128 + tid] = Yb1[tid];
    }
    __syncthreads();

    const int lane = tid & 63;
    const int wv   = tid >> 6;
    const int g    = lane >> 4;     // quad group 0..3
    const int c    = lane & 15;     // column within tile
    const int sG   = blockIdx.x * 256 + wv * 64 + lane;   // global sample
    const int k0   = g * 8;         // this lane's k-slice base (kc=0)

    // per-lane resident epilogue constants (n = c + 16*nt)
    float qb2[4], qw3[4], yb2[4], yw3[4];
    #pragma unroll
    for (int nt = 0; nt < 4; ++nt) {
        qb2[nt] = Qb2[c + 16 * nt]; qw3[nt] = Qw3[c + 16 * nt];
        yb2[nt] = Yb2[c + 16 * nt]; yw3[nt] = Yw3[c + 16 * nt];
    }
    const float qb3 = Qb3[0], yb3 = Yb3[0];

    float* xA = xbA[wv];
    float* xB = xbB[wv];

    float y = y0i[0];
    float Y0, dY0, loss = 0.f;

    // ---- Y-net eval (forward + tangent wrt y) at (tt, yy) -> per-sample Yo, dYo ----
    auto yphase = [&](float tt, float yy, float& Yo, float& dYo) {
        float a1[16], w1yv[16];
        #pragma unroll
        for (int h = 0; h < 2; ++h) {
            int kk = k0 + 32 * h;
            float4_t wt0 = *(const float4_t*)&l1y[kk];
            float4_t wt1 = *(const float4_t*)&l1y[kk + 4];
            float4_t wy0 = *(const float4_t*)&l1y[64 + kk];
            float4_t wy1 = *(const float4_t*)&l1y[64 + kk + 4];
            float4_t bb0 = *(const float4_t*)&l1y[128 + kk];
            float4_t bb1 = *(const float4_t*)&l1y[128 + kk + 4];
            #pragma unroll
            for (int j = 0; j < 4; ++j) {
                a1[8 * h + j]     = fmaf(tt, wt0[j], bb0[j]);
                a1[8 * h + 4 + j] = fmaf(tt, wt1[j], bb1[j]);
                w1yv[8 * h + j]     = wy0[j];
                w1yv[8 * h + 4 + j] = wy1[j];
            }
        }
        #pragma unroll
        for (int mt = 0; mt < 4; ++mt) {
            float ym = __shfl(yy, mt * 16 + c, 64);
            float hv[16], dv[16];
            #pragma unroll
            for (int j = 0; j < 16; ++j) {
                float v = fmaf(w1yv[j], ym, a1[j]);
                hv[j] = fmaxf(v, 0.f);
                dv[j] = (v > 0.f) ? w1yv[j] : 0.f;
            }
            H8 af0, af1, at0, at1;
            #pragma unroll
            for (int j = 0; j < 4; ++j) {
                af0.p[j] = __builtin_amdgcn_cvt_pkrtz(hv[2 * j],     hv[2 * j + 1]);
                af1.p[j] = __builtin_amdgcn_cvt_pkrtz(hv[8 + 2 * j], hv[8 + 2 * j + 1]);
                at0.p[j] = __builtin_amdgcn_cvt_pkrtz(dv[2 * j],     dv[2 * j + 1]);
                at1.p[j] = __builtin_amdgcn_cvt_pkrtz(dv[8 + 2 * j], dv[8 + 2 * j + 1]);
            }
            float4_t cf[4] = {}, ct[4] = {};
            #pragma unroll
            for (int nt = 0; nt < 4; ++nt) {
                const _Float16* bp = &w2y[(c + 16 * nt) * 72 + k0];
                half8_t b0h = *(const half8_t*)bp;
                half8_t b1h = *(const half8_t*)(bp + 32);
                cf[nt] = MFMA(af0.v, b0h, cf[nt]);
                cf[nt] = MFMA(af1.v, b1h, cf[nt]);
                ct[nt] = MFMA(at0.v, b0h, ct[nt]);
                ct[nt] = MFMA(at1.v, b1h, ct[nt]);
            }
            float pf[4] = {0, 0, 0, 0}, pd[4] = {0, 0, 0, 0};
            #pragma unroll
            for (int nt = 0; nt < 4; ++nt) {
                #pragma unroll
                for (int r = 0; r < 4; ++r) {
                    float pre = cf[nt][r] + yb2[nt];
                    float hh = fmaxf(pre, 0.f);
                    pf[r] = fmaf(hh, yw3[nt], pf[r]);
                    float dd = (pre > 0.f) ? ct[nt][r] : 0.f;
                    pd[r] = fmaf(dd, yw3[nt], pd[r]);
                }
            }
            #pragma unroll
            for (int r = 0; r < 4; ++r) {
                #pragma unroll
                for (int off = 1; off < 16; off <<= 1) {
                    pf[r] += __shfl_xor(pf[r], off, 16);
                    pd[r] += __shfl_xor(pd[r], off, 16);
                }
            }
            if (c == 0) {
                float4_t f4, d4;
                #pragma unroll
                for (int r = 0; r < 4; ++r) { f4[r] = pf[r] + yb3; d4[r] = pd[r]; }
                *(float4_t*)&xA[mt * 16 + g * 4] = f4;
                *(float4_t*)&xB[mt * 16 + g * 4] = d4;
            }
        }
        Yo  = xA[lane];
        dYo = xB[lane];
    };

    // init Y0, dY0 at (t=0, y0)
    yphase(0.f, y, Y0, dY0);

    float t = 0.f;
    for (int s = 0; s < NSTEPS; ++s) {
        float dw = dW[(size_t)s * B_TOT + sG];

        // ---- Q phase at (t, y) -> q0 per sample ----
        {
            float aq[16], wqy[16];
            #pragma unroll
            for (int h = 0; h < 2; ++h) {
                int kk = k0 + 32 * h;
                float4_t wt0 = *(const float4_t*)&l1q[kk];
                float4_t wt1 = *(const float4_t*)&l1q[kk + 4];
                float4_t wy0 = *(const float4_t*)&l1q[64 + kk];
                float4_t wy1 = *(const float4_t*)&l1q[64 + kk + 4];
                float4_t bb0 = *(const float4_t*)&l1q[128 + kk];
                float4_t bb1 = *(const float4_t*)&l1q[128 + kk + 4];
                #pragma unroll
                for (int j = 0; j < 4; ++j) {
                    aq[8 * h + j]     = fmaf(t, wt0[j], bb0[j]);
                    aq[8 * h + 4 + j] = fmaf(t, wt1[j], bb1[j]);
                    wqy[8 * h + j]     = wy0[j];
                    wqy[8 * h + 4 + j] = wy1[j];
                }
            }
            #pragma unroll
            for (int mt = 0; mt < 4; ++mt) {
                float ym = __shfl(y, mt * 16 + c, 64);
                float hv[16];
                #pragma unroll
                for (int j = 0; j < 16; ++j)
                    hv[j] = fmaxf(fmaf(wqy[j], ym, aq[j]), 0.f);
                H8 a0, a1h;
                #pragma unroll
                for (int j = 0; j < 4; ++j) {
                    a0.p[j]  = __builtin_amdgcn_cvt_pkrtz(hv[2 * j],     hv[2 * j + 1]);
                    a1h.p[j] = __builtin_amdgcn_cvt_pkrtz(hv[8 + 2 * j], hv[8 + 2 * j + 1]);
                }
                float4_t cq[4] = {};
                #pragma unroll
                for (int nt = 0; nt < 4; ++nt) {
                    const _Float16* bp = &w2q[(c + 16 * nt) * 72 + k0];
                    half8_t b0h = *(const half8_t*)bp;
                    half8_t b1h = *(const half8_t*)(bp + 32);
                    cq[nt] = MFMA(a0.v,  b0h, cq[nt]);
                    cq[nt] = MFMA(a1h.v, b1h, cq[nt]);
                }
                float p[4] = {0, 0, 0, 0};
                #pragma unroll
                for (int nt = 0; nt < 4; ++nt) {
                    #pragma unroll
                    for (int r = 0; r < 4; ++r) {
                        float v = fmaxf(cq[nt][r] + qb2[nt], 0.f);
                        p[r] = fmaf(v, qw3[nt], p[r]);
                    }
                }
                #pragma unroll
                for (int r = 0; r < 4; ++r) {
                    #pragma unroll
                    for (int off = 1; off < 16; off <<= 1)
                        p[r] += __shfl_xor(p[r], off, 16);
                }
                if (c == 0) {
                    float4_t f4;
                    #pragma unroll
                    for (int r = 0; r < 4; ++r) f4[r] = p[r] + qb3;
                    *(float4_t*)&xA[mt * 16 + g * 4] = f4;
                }
            }
        }
        float q0 = xA[lane];

        float y1 = fmaf(SIGMA, dw, fmaf(q0, DT, y));
        float t1 = t + DT;

        float Y1, dY1;
        yphase(t1, y1, Y1, dY1);

        // resid = Y1 - (Y0 - 0.5*q0^2*DT + SIGMA*dY0*dw)
        float resid = Y1 - (Y0 - 0.5f * q0 * q0 * DT + SIGMA * dY0 * dw);
        loss = fmaf(resid, resid, loss);

        y = y1; t = t1; Y0 = Y1; dY0 = dY1;
    }

    // terminal: (YN - yN^2)^2
    float tm = Y0 - y * y;
    loss = fmaf(tm, tm, loss);

    #pragma unroll
    for (int off = 1; off < 64; off <<= 1) loss += __shfl_xor(loss, off, 64);
    if (lane == 0) rb[wv] = loss;
    __syncthreads();
    if (tid == 0) atomicAdd(out, (rb[0] + rb[1] + rb[2] + rb[3]) * (1.0f / (float)B_TOT));
}

extern "C" void kernel_launch(void* const* d_in, const int* in_sizes, int n_in,
                              void* d_out, int out_size, void* d_ws, size_t ws_size,
                              hipStream_t stream) {
    const float* dW  = (const float*)d_in[0];
    const float* y0i = (const float*)d_in[1];
    const float* Yw1 = (const float*)d_in[2];
    const float* Yb1 = (const float*)d_in[3];
    const float* Yw2 = (const float*)d_in[4];
    const float* Yb2 = (const float*)d_in[5];
    const float* Yw3 = (const float*)d_in[6];
    const float* Yb3 = (const float*)d_in[7];
    const float* Qw1 = (const float*)d_in[8];
    const float* Qb1 = (const float*)d_in[9];
    const float* Qw2 = (const float*)d_in[10];
    const float* Qb2 = (const float*)d_in[11];
    const float* Qw3 = (const float*)d_in[12];
    const float* Qb3 = (const float*)d_in[13];
    float* out = (float*)d_out;

    hipLaunchKernelGGL(zero_out_k, dim3(1), dim3(1), 0, stream, out);
    hipLaunchKernelGGL(fbsnn_k, dim3(B_TOT / 256), dim3(256), 0, stream,
                       dW, y0i, Yw1, Yb1, Yw2, Yb2, Yw3, Yb3,
                       Qw1, Qb1, Qw2, Qb2, Qw3, Qb3, out);
}

// Round 3
// 933.961 us; speedup vs baseline: 1.2063x; 1.2063x over previous
//
#include <hip/hip_runtime.h>

// FBSNN: 50-step SDE loop, two 2-64-64-1 MLPs (Q control, Y value + dY/dy tangent).
// Wave = 64 samples for all 50 steps. 64x64 layers via mfma_f32_16x16x32_f16 (fp32 accum).
// R2 change: width-16 butterfly reductions -> DPP row_ror adds (VALU pipe, no ds_swizzle);
// dW load software-pipelined one step ahead.

#define B_TOT 262144
#define NSTEPS 50
#define DT 0.01f
#define SIGMA 0.5f

typedef _Float16 half8_t __attribute__((ext_vector_type(8)));
typedef __fp16   fp16x2  __attribute__((ext_vector_type(2)));
typedef float    float4_t __attribute__((ext_vector_type(4)));

union H8 { half8_t v; fp16x2 p[4]; };

#define MFMA(a, b, c) __builtin_amdgcn_mfma_f32_16x16x32_f16((a), (b), (c), 0, 0, 0)

// v_add_f32 with DPP row_ror operand: sums within the 16-lane row, VALU pipe only.
// ror1,ror2,ror4,ror8 => every lane of the row ends with the full 16-lane sum.
template<int CTRL>
__device__ __forceinline__ float dpp_add(float x) {
    union { int i; float f; } u, o;
    u.f = x;
    o.i = __builtin_amdgcn_update_dpp(0, u.i, CTRL, 0xF, 0xF, true);
    return x + o.f;
}
__device__ __forceinline__ float row_reduce16(float x) {
    x = dpp_add<0x121>(x);  // row_ror:1
    x = dpp_add<0x122>(x);  // row_ror:2
    x = dpp_add<0x124>(x);  // row_ror:4
    x = dpp_add<0x128>(x);  // row_ror:8
    return x;
}

__global__ void zero_out_k(float* out) { out[0] = 0.f; }

__global__ __launch_bounds__(256) void fbsnn_k(
    const float* __restrict__ dW,  const float* __restrict__ y0i,
    const float* __restrict__ Yw1, const float* __restrict__ Yb1,
    const float* __restrict__ Yw2, const float* __restrict__ Yb2,
    const float* __restrict__ Yw3, const float* __restrict__ Yb3,
    const float* __restrict__ Qw1, const float* __restrict__ Qb1,
    const float* __restrict__ Qw2, const float* __restrict__ Qb2,
    const float* __restrict__ Qw3, const float* __restrict__ Qb3,
    float* __restrict__ out)
{
    // W2 transposed: w2[n*72 + k] = W2[k*64 + n]; stride 72 (144B) keeps b128 aligned.
    __shared__ __align__(16) _Float16 w2q[64 * 72];
    __shared__ __align__(16) _Float16 w2y[64 * 72];
    // layer1 consts fp32: [0..63]=w1_t row, [64..127]=w1_y row, [128..191]=b1
    __shared__ __align__(16) float l1q[192];
    __shared__ __align__(16) float l1y[192];
    // per-wave sample-layout exchange buffers
    __shared__ __align__(16) float xbA[4][64];
    __shared__ __align__(16) float xbB[4][64];
    __shared__ float rb[4];

    const int tid = threadIdx.x;

    #pragma unroll
    for (int it = 0; it < 16; ++it) {
        int e = it * 256 + tid;
        int k = e >> 6, n = e & 63;
        w2q[n * 72 + k] = (_Float16)Qw2[e];
        w2y[n * 72 + k] = (_Float16)Yw2[e];
    }
    if (tid < 64) {
        l1q[tid] = Qw1[tid]; l1q[64 + tid] = Qw1[64 + tid]; l1q[128 + tid] = Qb1[tid];
        l1y[tid] = Yw1[tid]; l1y[64 + tid] = Yw1[64 + tid]; l1y[128 + tid] = Yb1[tid];
    }
    __syncthreads();

    const int lane = tid & 63;
    const int wv   = tid >> 6;
    const int g    = lane >> 4;     // quad group 0..3
    const int c    = lane & 15;     // column within tile
    const int sG   = blockIdx.x * 256 + wv * 64 + lane;   // global sample
    const int k0   = g * 8;         // this lane's k-slice base (kc=0)

    // per-lane resident epilogue constants (n = c + 16*nt)
    float qb2[4], qw3[4], yb2[4], yw3[4];
    #pragma unroll
    for (int nt = 0; nt < 4; ++nt) {
        qb2[nt] = Qb2[c + 16 * nt]; qw3[nt] = Qw3[c + 16 * nt];
        yb2[nt] = Yb2[c + 16 * nt]; yw3[nt] = Yw3[c + 16 * nt];
    }
    const float qb3 = Qb3[0], yb3 = Yb3[0];

    float* xA = xbA[wv];
    float* xB = xbB[wv];

    float y = y0i[0];
    float Y0, dY0, loss = 0.f;

    // ---- Y-net eval (forward + tangent wrt y) at (tt, yy) -> per-sample Yo, dYo ----
    auto yphase = [&](float tt, float yy, float& Yo, float& dYo) {
        float a1[16], w1yv[16];
        #pragma unroll
        for (int h = 0; h < 2; ++h) {
            int kk = k0 + 32 * h;
            float4_t wt0 = *(const float4_t*)&l1y[kk];
            float4_t wt1 = *(const float4_t*)&l1y[kk + 4];
            float4_t wy0 = *(const float4_t*)&l1y[64 + kk];
            float4_t wy1 = *(const float4_t*)&l1y[64 + kk + 4];
            float4_t bb0 = *(const float4_t*)&l1y[128 + kk];
            float4_t bb1 = *(const float4_t*)&l1y[128 + kk + 4];
            #pragma unroll
            for (int j = 0; j < 4; ++j) {
                a1[8 * h + j]     = fmaf(tt, wt0[j], bb0[j]);
                a1[8 * h + 4 + j] = fmaf(tt, wt1[j], bb1[j]);
                w1yv[8 * h + j]     = wy0[j];
                w1yv[8 * h + 4 + j] = wy1[j];
            }
        }
        #pragma unroll
        for (int mt = 0; mt < 4; ++mt) {
            float ym = __shfl(yy, mt * 16 + c, 64);
            float hv[16], dv[16];
            #pragma unroll
            for (int j = 0; j < 16; ++j) {
                float v = fmaf(w1yv[j], ym, a1[j]);
                hv[j] = fmaxf(v, 0.f);
                dv[j] = (v > 0.f) ? w1yv[j] : 0.f;
            }
            H8 af0, af1, at0, at1;
            #pragma unroll
            for (int j = 0; j < 4; ++j) {
                af0.p[j] = __builtin_amdgcn_cvt_pkrtz(hv[2 * j],     hv[2 * j + 1]);
                af1.p[j] = __builtin_amdgcn_cvt_pkrtz(hv[8 + 2 * j], hv[8 + 2 * j + 1]);
                at0.p[j] = __builtin_amdgcn_cvt_pkrtz(dv[2 * j],     dv[2 * j + 1]);
                at1.p[j] = __builtin_amdgcn_cvt_pkrtz(dv[8 + 2 * j], dv[8 + 2 * j + 1]);
            }
            float4_t cf[4] = {}, ct[4] = {};
            #pragma unroll
            for (int nt = 0; nt < 4; ++nt) {
                const _Float16* bp = &w2y[(c + 16 * nt) * 72 + k0];
                half8_t b0h = *(const half8_t*)bp;
                half8_t b1h = *(const half8_t*)(bp + 32);
                cf[nt] = MFMA(af0.v, b0h, cf[nt]);
                cf[nt] = MFMA(af1.v, b1h, cf[nt]);
                ct[nt] = MFMA(at0.v, b0h, ct[nt]);
                ct[nt] = MFMA(at1.v, b1h, ct[nt]);
            }
            float pf[4] = {0, 0, 0, 0}, pd[4] = {0, 0, 0, 0};
            #pragma unroll
            for (int nt = 0; nt < 4; ++nt) {
                #pragma unroll
                for (int r = 0; r < 4; ++r) {
                    float pre = cf[nt][r] + yb2[nt];
                    float hh = fmaxf(pre, 0.f);
                    pf[r] = fmaf(hh, yw3[nt], pf[r]);
                    float dd = (pre > 0.f) ? ct[nt][r] : 0.f;
                    pd[r] = fmaf(dd, yw3[nt], pd[r]);
                }
            }
            #pragma unroll
            for (int r = 0; r < 4; ++r) {
                pf[r] = row_reduce16(pf[r]);
                pd[r] = row_reduce16(pd[r]);
            }
            if (c == 0) {
                float4_t f4, d4;
                #pragma unroll
                for (int r = 0; r < 4; ++r) { f4[r] = pf[r] + yb3; d4[r] = pd[r]; }
                *(float4_t*)&xA[mt * 16 + g * 4] = f4;
                *(float4_t*)&xB[mt * 16 + g * 4] = d4;
            }
        }
        Yo  = xA[lane];
        dYo = xB[lane];
    };

    // init Y0, dY0 at (t=0, y0)
    yphase(0.f, y, Y0, dY0);

    float t = 0.f;
    float dw = dW[sG];  // prefetched for step 0
    for (int s = 0; s < NSTEPS; ++s) {
        // prefetch next step's dW early; latency hides under Q phase
        int sn = (s + 1 < NSTEPS) ? (s + 1) : (NSTEPS - 1);
        float dw_next = dW[(size_t)sn * B_TOT + sG];

        // ---- Q phase at (t, y) -> q0 per sample ----
        {
            float aq[16], wqy[16];
            #pragma unroll
            for (int h = 0; h < 2; ++h) {
                int kk = k0 + 32 * h;
                float4_t wt0 = *(const float4_t*)&l1q[kk];
                float4_t wt1 = *(const float4_t*)&l1q[kk + 4];
                float4_t wy0 = *(const float4_t*)&l1q[64 + kk];
                float4_t wy1 = *(const float4_t*)&l1q[64 + kk + 4];
                float4_t bb0 = *(const float4_t*)&l1q[128 + kk];
                float4_t bb1 = *(const float4_t*)&l1q[128 + kk + 4];
                #pragma unroll
                for (int j = 0; j < 4; ++j) {
                    aq[8 * h + j]     = fmaf(t, wt0[j], bb0[j]);
                    aq[8 * h + 4 + j] = fmaf(t, wt1[j], bb1[j]);
                    wqy[8 * h + j]     = wy0[j];
                    wqy[8 * h + 4 + j] = wy1[j];
                }
            }
            #pragma unroll
            for (int mt = 0; mt < 4; ++mt) {
                float ym = __shfl(y, mt * 16 + c, 64);
                float hv[16];
                #pragma unroll
                for (int j = 0; j < 16; ++j)
                    hv[j] = fmaxf(fmaf(wqy[j], ym, aq[j]), 0.f);
                H8 a0, a1h;
                #pragma unroll
                for (int j = 0; j < 4; ++j) {
                    a0.p[j]  = __builtin_amdgcn_cvt_pkrtz(hv[2 * j],     hv[2 * j + 1]);
                    a1h.p[j] = __builtin_amdgcn_cvt_pkrtz(hv[8 + 2 * j], hv[8 + 2 * j + 1]);
                }
                float4_t cq[4] = {};
                #pragma unroll
                for (int nt = 0; nt < 4; ++nt) {
                    const _Float16* bp = &w2q[(c + 16 * nt) * 72 + k0];
                    half8_t b0h = *(const half8_t*)bp;
                    half8_t b1h = *(const half8_t*)(bp + 32);
                    cq[nt] = MFMA(a0.v,  b0h, cq[nt]);
                    cq[nt] = MFMA(a1h.v, b1h, cq[nt]);
                }
                float p[4] = {0, 0, 0, 0};
                #pragma unroll
                for (int nt = 0; nt < 4; ++nt) {
                    #pragma unroll
                    for (int r = 0; r < 4; ++r) {
                        float v = fmaxf(cq[nt][r] + qb2[nt], 0.f);
                        p[r] = fmaf(v, qw3[nt], p[r]);
                    }
                }
                #pragma unroll
                for (int r = 0; r < 4; ++r)
                    p[r] = row_reduce16(p[r]);
                if (c == 0) {
                    float4_t f4;
                    #pragma unroll
                    for (int r = 0; r < 4; ++r) f4[r] = p[r] + qb3;
                    *(float4_t*)&xA[mt * 16 + g * 4] = f4;
                }
            }
        }
        float q0 = xA[lane];

        float y1 = fmaf(SIGMA, dw, fmaf(q0, DT, y));
        float t1 = t + DT;

        float Y1, dY1;
        yphase(t1, y1, Y1, dY1);

        // resid = Y1 - (Y0 - 0.5*q0^2*DT + SIGMA*dY0*dw)
        float resid = Y1 - (Y0 - 0.5f * q0 * q0 * DT + SIGMA * dY0 * dw);
        loss = fmaf(resid, resid, loss);

        y = y1; t = t1; Y0 = Y1; dY0 = dY1;
        dw = dw_next;
    }

    // terminal: (YN - yN^2)^2
    float tm = Y0 - y * y;
    loss = fmaf(tm, tm, loss);

    #pragma unroll
    for (int off = 1; off < 64; off <<= 1) loss += __shfl_xor(loss, off, 64);
    if (lane == 0) rb[wv] = loss;
    __syncthreads();
    if (tid == 0) atomicAdd(out, (rb[0] + rb[1] + rb[2] + rb[3]) * (1.0f / (float)B_TOT));
}

extern "C" void kernel_launch(void* const* d_in, const int* in_sizes, int n_in,
                              void* d_out, int out_size, void* d_ws, size_t ws_size,
                              hipStream_t stream) {
    const float* dW  = (const float*)d_in[0];
    const float* y0i = (const float*)d_in[1];
    const float* Yw1 = (const float*)d_in[2];
    const float* Yb1 = (const float*)d_in[3];
    const float* Yw2 = (const float*)d_in[4];
    const float* Yb2 = (const float*)d_in[5];
    const float* Yw3 = (const float*)d_in[6];
    const float* Yb3 = (const float*)d_in[7];
    const float* Qw1 = (const float*)d_in[8];
    const float* Qb1 = (const float*)d_in[9];
    const float* Qw2 = (const float*)d_in[10];
    const float* Qb2 = (const float*)d_in[11];
    const float* Qw3 = (const float*)d_in[12];
    const float* Qb3 = (const float*)d_in[13];
    float* out = (float*)d_out;

    hipLaunchKernelGGL(zero_out_k, dim3(1), dim3(1), 0, stream, out);
    hipLaunchKernelGGL(fbsnn_k, dim3(B_TOT / 256), dim3(256), 0, stream,
                       dW, y0i, Yw1, Yb1, Yw2, Yb2, Yw3, Yb3,
                       Qw1, Qb1, Qw2, Qb2, Qw3, Qb3, out);
}